// Round 1
// baseline (440.853 us; speedup 1.0000x reference)
//
#include <hip/hip_runtime.h>
#include <hip/hip_bf16.h>

#define UNITS 512
#define STEPS 100
#define BATCH 256
#define DTC 0.001f

typedef __attribute__((ext_vector_type(8))) short bf16x8;
typedef __attribute__((ext_vector_type(4))) float f32x4;

__device__ __forceinline__ void gload16(const void* g, void* l) {
  __builtin_amdgcn_global_load_lds(
      (const __attribute__((address_space(1))) void*)g,
      (__attribute__((address_space(3))) void*)l,
      16, 0, 0);
}

// ---------------- encoder (fp32, accuracy-critical) ----------------

__global__ void enc1(const float* __restrict__ ms_in, const float* __restrict__ rs_in,
                     const float* __restrict__ Wms, const float* __restrict__ bms,
                     const float* __restrict__ Wrs, const float* __restrict__ brs,
                     float* __restrict__ stcat) {
  int b = blockIdx.x;
  int n = threadIdx.x;  // 512
  __shared__ float s[192];
  if (n < 64) s[n] = ms_in[b * 64 + n];
  else if (n < 192) s[n] = rs_in[b * 128 + (n - 64)];
  __syncthreads();
  float acc;
  if (n < 256) {
    acc = bms[n];
    for (int k = 0; k < 64; ++k) acc += s[k] * Wms[k * 256 + n];
  } else {
    int nn = n - 256;
    acc = brs[nn];
    for (int k = 0; k < 128; ++k) acc += s[64 + k] * Wrs[k * 256 + nn];
  }
  stcat[b * 512 + n] = fmaxf(acc, 0.f);
}

__global__ void enc2(const float* __restrict__ stcat, const float* __restrict__ Wc,
                     const float* __restrict__ bc, float* __restrict__ st) {
  int b = blockIdx.x;
  int n = threadIdx.x;  // 512
  __shared__ float s[512];
  s[n] = stcat[b * 512 + n];
  __syncthreads();
  float acc = bc[n];
  for (int k = 0; k < 512; ++k) acc += s[k] * Wc[k * 512 + n];
  st[b * 512 + n] = fmaxf(acc, 0.f);
}

__global__ void enc3(const float* __restrict__ st,
                     const float* __restrict__ Wmu, const float* __restrict__ bmu,
                     const float* __restrict__ Wb, const float* __restrict__ bbias,
                     const float* __restrict__ Wom, const float* __restrict__ bom,
                     float* __restrict__ mu_out, float* __restrict__ bb_out,
                     float* __restrict__ om_out) {
  int b = blockIdx.x;
  int n = threadIdx.x;  // 512
  __shared__ float s[512];
  __shared__ float red[512];
  s[n] = st[b * 512 + n];
  __syncthreads();
  float am = bmu[n], ab = bbias[n];
  for (int k = 0; k < 512; ++k) {
    float sv = s[k];
    am += sv * Wmu[k * 512 + n];
    ab += sv * Wb[k * 512 + n];
  }
  mu_out[b * 512 + n] = fabsf(fmaxf(am, 0.f));
  bb_out[b * 512 + n] = fabsf(fmaxf(ab, 0.f));
  red[n] = s[n] * Wom[n];  // W_om is [512,1]
  __syncthreads();
  for (int off = 256; off > 0; off >>= 1) {
    if (n < off) red[n] += red[n + off];
    __syncthreads();
  }
  if (n == 0) om_out[b] = fabsf(fmaxf(red[0] + bom[0], 0.f));
}

// ---------------- weight transpose+pack (fp32 -> bf16 B^T quadrants) ----------------

__global__ void tpack(const float* __restrict__ src, int R, int C, float sign,
                      __hip_bfloat16* __restrict__ dst, int ds) {
  // dst[c*ds + r] = bf16(sign * src[r*C + c])
  __shared__ float tile[32][33];
  int cb = blockIdx.x * 32, rb = blockIdx.y * 32;
  int tx = threadIdx.x, ty = threadIdx.y;  // (32,8)
#pragma unroll
  for (int i = 0; i < 32; i += 8)
    tile[ty + i][tx] = src[(size_t)(rb + ty + i) * C + (cb + tx)];
  __syncthreads();
#pragma unroll
  for (int i = 0; i < 32; i += 8)
    dst[(size_t)(cb + ty + i) * ds + (rb + tx)] = __float2bfloat16(sign * tile[tx][ty + i]);
}

// ---------------- Hopf trajectory (fp32 state; emits bf16 GEMM input) ----------------

__global__ void hopf_traj(const float* __restrict__ z, const float* __restrict__ omega,
                          const float* __restrict__ mu, const float* __restrict__ bb,
                          __hip_bfloat16* __restrict__ A0, float* __restrict__ z_out) {
  int b = blockIdx.x;
  int j = threadIdx.x;  // 512
  float x = z[b * 1024 + j];
  float y = z[b * 1024 + 512 + j];
  float om = omega[b];
  float muv = mu[b * 512 + j];
  float bbv = bb[b * 512 + j];
  float w = om * (float)(j + 1);
  for (int t = 0; t < STEPS; ++t) {
    float r2 = x * x + y * y;
    float g = muv - r2;
    float nx = x + DTC * (g * x - w * y + bbv);
    float ny = y + DTC * (g * y + w * x);
    x = nx; y = ny;
    if (t == 0) {
      z_out[b * 1024 + j] = x;
      z_out[b * 1024 + 512 + j] = y;
    }
    size_t row = (size_t)b * STEPS + t;  // M-order: m = b*100 + t
    A0[row * 1024 + j] = __float2bfloat16(x);
    A0[row * 1024 + 512 + j] = __float2bfloat16(y);
  }
}

// ---------------- bf16 MFMA GEMM: C = relu(A @ BT^T + bias) ----------------
// A [M,K] row-major bf16; BT [N,K] row-major bf16. 128x128 tile, 4 waves (2x2),
// BK=32, global_load_lds width-16 staging, 16x16x32 bf16 MFMA.

template <int OUT_BF16>
__global__ __launch_bounds__(256)
void gemm_bt(const __hip_bfloat16* __restrict__ A, const __hip_bfloat16* __restrict__ BT,
             const float* __restrict__ biasA, const float* __restrict__ biasB, int bsplit,
             void* __restrict__ Cout, int M, int N, int K) {
  __shared__ __align__(16) __hip_bfloat16 As[128 * 32];
  __shared__ __align__(16) __hip_bfloat16 Bs[128 * 32];
  const int tid = threadIdx.x;
  const int lane = tid & 63;
  const int wid = tid >> 6;
  const int wr = wid >> 1, wc = wid & 1;
  const int fr = lane & 15, fq = lane >> 4;
  const int m0 = blockIdx.y * 128;
  const int n0 = blockIdx.x * 128;

  // staging: chunk c = tid (and tid+256): row c/4, k-part (c%4)*8, LDS byte c*16
  const __hip_bfloat16* Ag = A + (size_t)(m0 + (tid >> 2)) * K + (tid & 3) * 8;
  const __hip_bfloat16* Ag2 = Ag + (size_t)64 * K;
  const __hip_bfloat16* Bg = BT + (size_t)(n0 + (tid >> 2)) * K + (tid & 3) * 8;
  const __hip_bfloat16* Bg2 = Bg + (size_t)64 * K;
  char* AsB = (char*)&As[0] + wid * 1024;
  char* BsB = (char*)&Bs[0] + wid * 1024;

  f32x4 acc[4][4] = {};

  const int ksteps = K >> 5;
  for (int ks = 0; ks < ksteps; ++ks) {
    __syncthreads();  // prior reads done before overwrite
    gload16(Ag, AsB);
    gload16(Ag2, AsB + 4096);
    gload16(Bg, BsB);
    gload16(Bg2, BsB + 4096);
    Ag += 32; Ag2 += 32; Bg += 32; Bg2 += 32;
    __syncthreads();  // drains vmcnt -> staged data visible

    bf16x8 af[4], bfr[4];
#pragma unroll
    for (int i = 0; i < 4; ++i)
      af[i] = *(const bf16x8*)&As[(wr * 64 + i * 16 + fr) * 32 + fq * 8];
#pragma unroll
    for (int j = 0; j < 4; ++j)
      bfr[j] = *(const bf16x8*)&Bs[(wc * 64 + j * 16 + fr) * 32 + fq * 8];
#pragma unroll
    for (int i = 0; i < 4; ++i)
#pragma unroll
      for (int j = 0; j < 4; ++j)
        acc[i][j] = __builtin_amdgcn_mfma_f32_16x16x32_bf16(af[i], bfr[j], acc[i][j], 0, 0, 0);
  }

  // epilogue: C/D layout col=lane&15, row=(lane>>4)*4+reg
#pragma unroll
  for (int j = 0; j < 4; ++j) {
    int col = n0 + wc * 64 + j * 16 + fr;
    float bv = (col < bsplit) ? biasA[col] : biasB[col - bsplit];
#pragma unroll
    for (int i = 0; i < 4; ++i) {
#pragma unroll
      for (int r = 0; r < 4; ++r) {
        int row = m0 + wr * 64 + i * 16 + fq * 4 + r;
        float v = fmaxf(acc[i][j][r] + bv, 0.f);
        if (OUT_BF16)
          ((__hip_bfloat16*)Cout)[(size_t)row * N + col] = __float2bfloat16(v);
        else
          ((float*)Cout)[(size_t)row * N + col] = v;
      }
    }
  }
}

// ---------------- launch ----------------

extern "C" void kernel_launch(void* const* d_in, const int* in_sizes, int n_in,
                              void* d_out, int out_size, void* d_ws, size_t ws_size,
                              hipStream_t stream) {
  const float* motion = (const float*)d_in[0];
  const float* robot  = (const float*)d_in[1];
  const float* z      = (const float*)d_in[2];
  const float* W_ms   = (const float*)d_in[3];
  const float* b_ms   = (const float*)d_in[4];
  const float* W_rs   = (const float*)d_in[5];
  const float* b_rs   = (const float*)d_in[6];
  const float* W_cmb  = (const float*)d_in[7];
  const float* b_cmb  = (const float*)d_in[8];
  const float* W_om   = (const float*)d_in[9];
  const float* b_om   = (const float*)d_in[10];
  const float* W_mu   = (const float*)d_in[11];
  const float* b_mu   = (const float*)d_in[12];
  const float* W_b    = (const float*)d_in[13];
  const float* b_b    = (const float*)d_in[14];
  const float* Wr0    = (const float*)d_in[15];
  const float* Wi0    = (const float*)d_in[16];
  const float* br0    = (const float*)d_in[17];
  const float* bi0    = (const float*)d_in[18];
  const float* Wr1    = (const float*)d_in[19];
  const float* Wi1    = (const float*)d_in[20];
  const float* br1    = (const float*)d_in[21];
  const float* bi1    = (const float*)d_in[22];
  const float* Wr2    = (const float*)d_in[23];
  const float* Wi2    = (const float*)d_in[24];
  const float* br2    = (const float*)d_in[25];
  // bi2 (d_in[26]) unused: yi of last layer is sliced away by [:, :, :256]

  float* out  = (float*)d_out;            // [25600,256], m = b*100+t
  float* zout = out + (size_t)6553600;    // [256,1024]
  float* omg  = zout + 262144;            // [256]
  float* muo  = omg + 256;                // [256,512]
  float* bbo  = muo + 131072;             // [256,512]

  char* ws = (char*)d_ws;
  float* stcat = (float*)ws;                               // 256*512 f32
  float* st    = stcat + 256 * 512;                        // 256*512 f32
  __hip_bfloat16* BT0 = (__hip_bfloat16*)(st + 256 * 512); // [2048,1024]
  __hip_bfloat16* BT1 = BT0 + (size_t)2048 * 1024;         // [1024,2048]
  __hip_bfloat16* BT2 = BT1 + (size_t)1024 * 2048;         // [256,1024]
  __hip_bfloat16* A0  = BT2 + (size_t)256 * 1024;          // [25600,1024]
  __hip_bfloat16* C1  = A0 + (size_t)25600 * 1024;         // [25600,2048]
  __hip_bfloat16* C2  = C1 + (size_t)25600 * 2048;         // [25600,1024]

  enc1<<<256, 512, 0, stream>>>(motion, robot, W_ms, b_ms, W_rs, b_rs, stcat);
  enc2<<<256, 512, 0, stream>>>(stcat, W_cmb, b_cmb, st);
  enc3<<<256, 512, 0, stream>>>(st, W_mu, b_mu, W_b, b_b, W_om, b_om, muo, bbo, omg);

  dim3 tb(32, 8);
  // BT0 = [[Wr0, Wi0], [-Wi0, Wr0]]^T   (Wr0/Wi0: [512,1024])
  tpack<<<dim3(32, 16), tb, 0, stream>>>(Wr0, 512, 1024,  1.f, BT0, 1024);
  tpack<<<dim3(32, 16), tb, 0, stream>>>(Wi0, 512, 1024,  1.f, BT0 + (size_t)1024 * 1024, 1024);
  tpack<<<dim3(32, 16), tb, 0, stream>>>(Wi0, 512, 1024, -1.f, BT0 + 512, 1024);
  tpack<<<dim3(32, 16), tb, 0, stream>>>(Wr0, 512, 1024,  1.f, BT0 + (size_t)1024 * 1024 + 512, 1024);
  // BT1 (Wr1/Wi1: [1024,512])
  tpack<<<dim3(16, 32), tb, 0, stream>>>(Wr1, 1024, 512,  1.f, BT1, 2048);
  tpack<<<dim3(16, 32), tb, 0, stream>>>(Wi1, 1024, 512,  1.f, BT1 + (size_t)512 * 2048, 2048);
  tpack<<<dim3(16, 32), tb, 0, stream>>>(Wi1, 1024, 512, -1.f, BT1 + 1024, 2048);
  tpack<<<dim3(16, 32), tb, 0, stream>>>(Wr1, 1024, 512,  1.f, BT1 + (size_t)512 * 2048 + 1024, 2048);
  // BT2 = [Wr2; -Wi2]^T  (Wr2/Wi2: [512,256])
  tpack<<<dim3(8, 16), tb, 0, stream>>>(Wr2, 512, 256,  1.f, BT2, 1024);
  tpack<<<dim3(8, 16), tb, 0, stream>>>(Wi2, 512, 256, -1.f, BT2 + 512, 1024);

  hopf_traj<<<256, 512, 0, stream>>>(z, omg, muo, bbo, A0, zout);

  gemm_bt<1><<<dim3(16, 200), 256, 0, stream>>>(A0, BT0, br0, bi0, 1024, C1, 25600, 2048, 1024);
  gemm_bt<1><<<dim3(8, 200), 256, 0, stream>>>(C1, BT1, br1, bi1, 512, C2, 25600, 1024, 2048);
  gemm_bt<0><<<dim3(2, 200), 256, 0, stream>>>(C2, BT2, br2, br2, 256, out, 25600, 256, 1024);
}

// Round 2
// 440.662 us; speedup vs baseline: 1.0004x; 1.0004x over previous
//
#include <hip/hip_runtime.h>
#include <hip/hip_bf16.h>

#define UNITS 512
#define STEPS 100
#define BATCH 256
#define DTC 0.001f

typedef __attribute__((ext_vector_type(8))) short bf16x8;
typedef __attribute__((ext_vector_type(4))) float f32x4;

__device__ __forceinline__ void gload16(const void* g, void* l) {
  __builtin_amdgcn_global_load_lds(
      (const __attribute__((address_space(1))) void*)g,
      (__attribute__((address_space(3))) void*)l,
      16, 0, 0);
}

// ---------------- encoder (fp32, accuracy-critical) ----------------

__global__ void enc1(const float* __restrict__ ms_in, const float* __restrict__ rs_in,
                     const float* __restrict__ Wms, const float* __restrict__ bms,
                     const float* __restrict__ Wrs, const float* __restrict__ brs,
                     float* __restrict__ stcat) {
  int b = blockIdx.x;
  int n = threadIdx.x;  // 512
  __shared__ float s[192];
  if (n < 64) s[n] = ms_in[b * 64 + n];
  else if (n < 192) s[n] = rs_in[b * 128 + (n - 64)];
  __syncthreads();
  float acc;
  if (n < 256) {
    acc = bms[n];
    for (int k = 0; k < 64; ++k) acc += s[k] * Wms[k * 256 + n];
  } else {
    int nn = n - 256;
    acc = brs[nn];
    for (int k = 0; k < 128; ++k) acc += s[64 + k] * Wrs[k * 256 + nn];
  }
  stcat[b * 512 + n] = fmaxf(acc, 0.f);
}

__global__ void enc2(const float* __restrict__ stcat, const float* __restrict__ Wc,
                     const float* __restrict__ bc, float* __restrict__ st) {
  int b = blockIdx.x;
  int n = threadIdx.x;  // 512
  __shared__ float s[512];
  s[n] = stcat[b * 512 + n];
  __syncthreads();
  float acc = bc[n];
  for (int k = 0; k < 512; ++k) acc += s[k] * Wc[k * 512 + n];
  st[b * 512 + n] = fmaxf(acc, 0.f);
}

__global__ void enc3(const float* __restrict__ st,
                     const float* __restrict__ Wmu, const float* __restrict__ bmu,
                     const float* __restrict__ Wb, const float* __restrict__ bbias,
                     const float* __restrict__ Wom, const float* __restrict__ bom,
                     float* __restrict__ mu_out, float* __restrict__ bb_out,
                     float* __restrict__ om_out) {
  int b = blockIdx.x;
  int n = threadIdx.x;  // 512
  __shared__ float s[512];
  __shared__ float red[512];
  s[n] = st[b * 512 + n];
  __syncthreads();
  float am = bmu[n], ab = bbias[n];
  for (int k = 0; k < 512; ++k) {
    float sv = s[k];
    am += sv * Wmu[k * 512 + n];
    ab += sv * Wb[k * 512 + n];
  }
  mu_out[b * 512 + n] = fabsf(fmaxf(am, 0.f));
  bb_out[b * 512 + n] = fabsf(fmaxf(ab, 0.f));
  red[n] = s[n] * Wom[n];  // W_om is [512,1]
  __syncthreads();
  for (int off = 256; off > 0; off >>= 1) {
    if (n < off) red[n] += red[n + off];
    __syncthreads();
  }
  if (n == 0) om_out[b] = fabsf(fmaxf(red[0] + bom[0], 0.f));
}

// ---------------- weight transpose+pack (fp32 -> bf16 B^T quadrants) ----------------

__global__ void tpack(const float* __restrict__ src, int R, int C, float sign,
                      __hip_bfloat16* __restrict__ dst, int ds) {
  // dst[c*ds + r] = bf16(sign * src[r*C + c])
  __shared__ float tile[32][33];
  int cb = blockIdx.x * 32, rb = blockIdx.y * 32;
  int tx = threadIdx.x, ty = threadIdx.y;  // (32,8)
#pragma unroll
  for (int i = 0; i < 32; i += 8)
    tile[ty + i][tx] = src[(size_t)(rb + ty + i) * C + (cb + tx)];
  __syncthreads();
#pragma unroll
  for (int i = 0; i < 32; i += 8)
    dst[(size_t)(cb + ty + i) * ds + (rb + tx)] = __float2bfloat16(sign * tile[tx][ty + i]);
}

// ---------------- Hopf trajectory (fp32 state; emits bf16 GEMM input) ----------------

__global__ void hopf_traj(const float* __restrict__ z, const float* __restrict__ omega,
                          const float* __restrict__ mu, const float* __restrict__ bb,
                          __hip_bfloat16* __restrict__ A0, float* __restrict__ z_out) {
  int b = blockIdx.x;
  int j = threadIdx.x;  // 512
  float x = z[b * 1024 + j];
  float y = z[b * 1024 + 512 + j];
  float om = omega[b];
  float muv = mu[b * 512 + j];
  float bbv = bb[b * 512 + j];
  float w = om * (float)(j + 1);
  for (int t = 0; t < STEPS; ++t) {
    float r2 = x * x + y * y;
    float g = muv - r2;
    float nx = x + DTC * (g * x - w * y + bbv);
    float ny = y + DTC * (g * y + w * x);
    x = nx; y = ny;
    if (t == 0) {
      z_out[b * 1024 + j] = x;
      z_out[b * 1024 + 512 + j] = y;
    }
    size_t row = (size_t)b * STEPS + t;  // M-order: m = b*100 + t
    A0[row * 1024 + j] = __float2bfloat16(x);
    A0[row * 1024 + 512 + j] = __float2bfloat16(y);
  }
}

// ---------------- bf16 MFMA GEMM: C = relu(A @ BT^T + bias) ----------------
// A [M,K] row-major bf16; BT [N,K] row-major bf16. 128x128 tile, 4 waves (2x2),
// BK=32, global_load_lds width-16 staging, 16x16x32 bf16 MFMA.

template <int OUT_BF16>
__global__ __launch_bounds__(256)
void gemm_bt(const __hip_bfloat16* __restrict__ A, const __hip_bfloat16* __restrict__ BT,
             const float* __restrict__ biasA, const float* __restrict__ biasB, int bsplit,
             void* __restrict__ Cout, int M, int N, int K) {
  __shared__ __align__(16) __hip_bfloat16 As[128 * 32];
  __shared__ __align__(16) __hip_bfloat16 Bs[128 * 32];
  const int tid = threadIdx.x;
  const int lane = tid & 63;
  const int wid = tid >> 6;
  const int wr = wid >> 1, wc = wid & 1;
  const int fr = lane & 15, fq = lane >> 4;
  const int m0 = blockIdx.y * 128;
  const int n0 = blockIdx.x * 128;

  // staging: chunk c = tid (and tid+256): row c/4, k-part (c%4)*8, LDS byte c*16
  const __hip_bfloat16* Ag = A + (size_t)(m0 + (tid >> 2)) * K + (tid & 3) * 8;
  const __hip_bfloat16* Ag2 = Ag + (size_t)64 * K;
  const __hip_bfloat16* Bg = BT + (size_t)(n0 + (tid >> 2)) * K + (tid & 3) * 8;
  const __hip_bfloat16* Bg2 = Bg + (size_t)64 * K;
  char* AsB = (char*)&As[0] + wid * 1024;
  char* BsB = (char*)&Bs[0] + wid * 1024;

  f32x4 acc[4][4] = {};

  const int ksteps = K >> 5;
  for (int ks = 0; ks < ksteps; ++ks) {
    __syncthreads();  // prior reads done before overwrite
    gload16(Ag, AsB);
    gload16(Ag2, AsB + 4096);
    gload16(Bg, BsB);
    gload16(Bg2, BsB + 4096);
    Ag += 32; Ag2 += 32; Bg += 32; Bg2 += 32;
    __syncthreads();  // drains vmcnt -> staged data visible

    bf16x8 af[4], bfr[4];
#pragma unroll
    for (int i = 0; i < 4; ++i)
      af[i] = *(const bf16x8*)&As[(wr * 64 + i * 16 + fr) * 32 + fq * 8];
#pragma unroll
    for (int j = 0; j < 4; ++j)
      bfr[j] = *(const bf16x8*)&Bs[(wc * 64 + j * 16 + fr) * 32 + fq * 8];
#pragma unroll
    for (int i = 0; i < 4; ++i)
#pragma unroll
      for (int j = 0; j < 4; ++j)
        acc[i][j] = __builtin_amdgcn_mfma_f32_16x16x32_bf16(af[i], bfr[j], acc[i][j], 0, 0, 0);
  }

  // epilogue: C/D layout col=lane&15, row=(lane>>4)*4+reg
#pragma unroll
  for (int j = 0; j < 4; ++j) {
    int col = n0 + wc * 64 + j * 16 + fr;
    float bv = (col < bsplit) ? biasA[col] : biasB[col - bsplit];
#pragma unroll
    for (int i = 0; i < 4; ++i) {
#pragma unroll
      for (int r = 0; r < 4; ++r) {
        int row = m0 + wr * 64 + i * 16 + fq * 4 + r;
        float v = fmaxf(acc[i][j][r] + bv, 0.f);
        if (OUT_BF16)
          ((__hip_bfloat16*)Cout)[(size_t)row * N + col] = __float2bfloat16(v);
        else
          ((float*)Cout)[(size_t)row * N + col] = v;
      }
    }
  }
}

// ---------------- launch ----------------

extern "C" void kernel_launch(void* const* d_in, const int* in_sizes, int n_in,
                              void* d_out, int out_size, void* d_ws, size_t ws_size,
                              hipStream_t stream) {
  const float* motion = (const float*)d_in[0];
  const float* robot  = (const float*)d_in[1];
  const float* z      = (const float*)d_in[2];
  const float* W_ms   = (const float*)d_in[3];
  const float* b_ms   = (const float*)d_in[4];
  const float* W_rs   = (const float*)d_in[5];
  const float* b_rs   = (const float*)d_in[6];
  const float* W_cmb  = (const float*)d_in[7];
  const float* b_cmb  = (const float*)d_in[8];
  const float* W_om   = (const float*)d_in[9];
  const float* b_om   = (const float*)d_in[10];
  const float* W_mu   = (const float*)d_in[11];
  const float* b_mu   = (const float*)d_in[12];
  const float* W_b    = (const float*)d_in[13];
  const float* b_b    = (const float*)d_in[14];
  const float* Wr0    = (const float*)d_in[15];
  const float* Wi0    = (const float*)d_in[16];
  const float* br0    = (const float*)d_in[17];
  const float* bi0    = (const float*)d_in[18];
  const float* Wr1    = (const float*)d_in[19];
  const float* Wi1    = (const float*)d_in[20];
  const float* br1    = (const float*)d_in[21];
  const float* bi1    = (const float*)d_in[22];
  const float* Wr2    = (const float*)d_in[23];
  const float* Wi2    = (const float*)d_in[24];
  const float* br2    = (const float*)d_in[25];
  // bi2 (d_in[26]) unused: yi of last layer is sliced away by [:, :, :256]

  float* out  = (float*)d_out;            // [25600,256], m = b*100+t
  float* zout = out + (size_t)6553600;    // [256,1024]
  float* omg  = zout + 262144;            // [256]
  float* muo  = omg + 256;                // [256,512]
  float* bbo  = muo + 131072;             // [256,512]

  char* ws = (char*)d_ws;
  float* stcat = (float*)ws;                               // 256*512 f32
  float* st    = stcat + 256 * 512;                        // 256*512 f32
  __hip_bfloat16* BT0 = (__hip_bfloat16*)(st + 256 * 512); // [2048,1024]
  __hip_bfloat16* BT1 = BT0 + (size_t)2048 * 1024;         // [1024,2048]
  __hip_bfloat16* BT2 = BT1 + (size_t)1024 * 2048;         // [256,1024]
  __hip_bfloat16* A0  = BT2 + (size_t)256 * 1024;          // [25600,1024]
  __hip_bfloat16* C1  = A0 + (size_t)25600 * 1024;         // [25600,2048]
  __hip_bfloat16* C2  = C1 + (size_t)25600 * 2048;         // [25600,1024]

  enc1<<<256, 512, 0, stream>>>(motion, robot, W_ms, b_ms, W_rs, b_rs, stcat);
  enc2<<<256, 512, 0, stream>>>(stcat, W_cmb, b_cmb, st);
  enc3<<<256, 512, 0, stream>>>(st, W_mu, b_mu, W_b, b_b, W_om, b_om, muo, bbo, omg);

  dim3 tb(32, 8);
  // BT0 = [[Wr0, Wi0], [-Wi0, Wr0]]^T   (Wr0/Wi0: [512,1024])
  tpack<<<dim3(32, 16), tb, 0, stream>>>(Wr0, 512, 1024,  1.f, BT0, 1024);
  tpack<<<dim3(32, 16), tb, 0, stream>>>(Wi0, 512, 1024,  1.f, BT0 + (size_t)1024 * 1024, 1024);
  tpack<<<dim3(32, 16), tb, 0, stream>>>(Wi0, 512, 1024, -1.f, BT0 + 512, 1024);
  tpack<<<dim3(32, 16), tb, 0, stream>>>(Wr0, 512, 1024,  1.f, BT0 + (size_t)1024 * 1024 + 512, 1024);
  // BT1 (Wr1/Wi1: [1024,512])
  tpack<<<dim3(16, 32), tb, 0, stream>>>(Wr1, 1024, 512,  1.f, BT1, 2048);
  tpack<<<dim3(16, 32), tb, 0, stream>>>(Wi1, 1024, 512,  1.f, BT1 + (size_t)512 * 2048, 2048);
  tpack<<<dim3(16, 32), tb, 0, stream>>>(Wi1, 1024, 512, -1.f, BT1 + 1024, 2048);
  tpack<<<dim3(16, 32), tb, 0, stream>>>(Wr1, 1024, 512,  1.f, BT1 + (size_t)512 * 2048 + 1024, 2048);
  // BT2 = [Wr2; -Wi2]^T  (Wr2/Wi2: [512,256])
  tpack<<<dim3(8, 16), tb, 0, stream>>>(Wr2, 512, 256,  1.f, BT2, 1024);
  tpack<<<dim3(8, 16), tb, 0, stream>>>(Wi2, 512, 256, -1.f, BT2 + 512, 1024);

  hopf_traj<<<256, 512, 0, stream>>>(z, omg, muo, bbo, A0, zout);

  gemm_bt<1><<<dim3(16, 200), 256, 0, stream>>>(A0, BT0, br0, bi0, 1024, C1, 25600, 2048, 1024);
  gemm_bt<1><<<dim3(8, 200), 256, 0, stream>>>(C1, BT1, br1, bi1, 512, C2, 25600, 1024, 2048);
  gemm_bt<0><<<dim3(2, 200), 256, 0, stream>>>(C2, BT2, br2, br2, 256, out, 25600, 256, 1024);
}

// Round 3
// 429.513 us; speedup vs baseline: 1.0264x; 1.0260x over previous
//
#include <hip/hip_runtime.h>
#include <hip/hip_bf16.h>

#define UNITS 512
#define STEPS 100
#define BATCH 256
#define DTC 0.001f

typedef __attribute__((ext_vector_type(8))) short bf16x8;
typedef __attribute__((ext_vector_type(4))) float f32x4;

__device__ __forceinline__ void gload16(const void* g, void* l) {
  __builtin_amdgcn_global_load_lds(
      (const __attribute__((address_space(1))) void*)g,
      (__attribute__((address_space(3))) void*)l,
      16, 0, 0);
}

// ---------------- encoder (fp32, accuracy-critical) ----------------

__global__ void enc1(const float* __restrict__ ms_in, const float* __restrict__ rs_in,
                     const float* __restrict__ Wms, const float* __restrict__ bms,
                     const float* __restrict__ Wrs, const float* __restrict__ brs,
                     float* __restrict__ stcat) {
  int b = blockIdx.x;
  int n = threadIdx.x;  // 512
  __shared__ float s[192];
  if (n < 64) s[n] = ms_in[b * 64 + n];
  else if (n < 192) s[n] = rs_in[b * 128 + (n - 64)];
  __syncthreads();
  float acc;
  if (n < 256) {
    acc = bms[n];
    for (int k = 0; k < 64; ++k) acc += s[k] * Wms[k * 256 + n];
  } else {
    int nn = n - 256;
    acc = brs[nn];
    for (int k = 0; k < 128; ++k) acc += s[64 + k] * Wrs[k * 256 + nn];
  }
  stcat[b * 512 + n] = fmaxf(acc, 0.f);
}

__global__ void enc2(const float* __restrict__ stcat, const float* __restrict__ Wc,
                     const float* __restrict__ bc, float* __restrict__ st) {
  int b = blockIdx.x;
  int n = threadIdx.x;  // 512
  __shared__ float s[512];
  s[n] = stcat[b * 512 + n];
  __syncthreads();
  float acc = bc[n];
  for (int k = 0; k < 512; ++k) acc += s[k] * Wc[k * 512 + n];
  st[b * 512 + n] = fmaxf(acc, 0.f);
}

__global__ void enc3(const float* __restrict__ st,
                     const float* __restrict__ Wmu, const float* __restrict__ bmu,
                     const float* __restrict__ Wb, const float* __restrict__ bbias,
                     const float* __restrict__ Wom, const float* __restrict__ bom,
                     float* __restrict__ mu_out, float* __restrict__ bb_out,
                     float* __restrict__ om_out) {
  int b = blockIdx.x;
  int n = threadIdx.x;  // 512
  __shared__ float s[512];
  __shared__ float red[512];
  s[n] = st[b * 512 + n];
  __syncthreads();
  float am = bmu[n], ab = bbias[n];
  for (int k = 0; k < 512; ++k) {
    float sv = s[k];
    am += sv * Wmu[k * 512 + n];
    ab += sv * Wb[k * 512 + n];
  }
  mu_out[b * 512 + n] = fabsf(fmaxf(am, 0.f));
  bb_out[b * 512 + n] = fabsf(fmaxf(ab, 0.f));
  red[n] = s[n] * Wom[n];  // W_om is [512,1]
  __syncthreads();
  for (int off = 256; off > 0; off >>= 1) {
    if (n < off) red[n] += red[n + off];
    __syncthreads();
  }
  if (n == 0) om_out[b] = fabsf(fmaxf(red[0] + bom[0], 0.f));
}

// ---------------- weight transpose+pack (fp32 -> bf16 B^T quadrants) ----------------

__global__ void tpack(const float* __restrict__ src, int R, int C, float sign,
                      __hip_bfloat16* __restrict__ dst, int ds) {
  // dst[c*ds + r] = bf16(sign * src[r*C + c])
  __shared__ float tile[32][33];
  int cb = blockIdx.x * 32, rb = blockIdx.y * 32;
  int tx = threadIdx.x, ty = threadIdx.y;  // (32,8)
#pragma unroll
  for (int i = 0; i < 32; i += 8)
    tile[ty + i][tx] = src[(size_t)(rb + ty + i) * C + (cb + tx)];
  __syncthreads();
#pragma unroll
  for (int i = 0; i < 32; i += 8)
    dst[(size_t)(cb + ty + i) * ds + (rb + tx)] = __float2bfloat16(sign * tile[tx][ty + i]);
}

// ---------------- Hopf trajectory (fp32 state; emits bf16 GEMM input) ----------------

__global__ void hopf_traj(const float* __restrict__ z, const float* __restrict__ omega,
                          const float* __restrict__ mu, const float* __restrict__ bb,
                          __hip_bfloat16* __restrict__ A0, float* __restrict__ z_out) {
  int b = blockIdx.x;
  int j = threadIdx.x;  // 512
  float x = z[b * 1024 + j];
  float y = z[b * 1024 + 512 + j];
  float om = omega[b];
  float muv = mu[b * 512 + j];
  float bbv = bb[b * 512 + j];
  float w = om * (float)(j + 1);
  for (int t = 0; t < STEPS; ++t) {
    float r2 = x * x + y * y;
    float g = muv - r2;
    float nx = x + DTC * (g * x - w * y + bbv);
    float ny = y + DTC * (g * y + w * x);
    x = nx; y = ny;
    if (t == 0) {
      z_out[b * 1024 + j] = x;
      z_out[b * 1024 + 512 + j] = y;
    }
    size_t row = (size_t)b * STEPS + t;  // M-order: m = b*100 + t
    A0[row * 1024 + j] = __float2bfloat16(x);
    A0[row * 1024 + 512 + j] = __float2bfloat16(y);
  }
}

// ---------------- bf16 MFMA GEMM: C = relu(A @ BT^T + bias) ----------------
// A [M,K] row-major bf16; BT [N,K] row-major bf16. 128x128 tile, 4 waves (2x2),
// BK=32, global_load_lds width-16 staging, 16x16x32 bf16 MFMA.

template <int OUT_BF16>
__global__ __launch_bounds__(256)
void gemm_bt(const __hip_bfloat16* __restrict__ A, const __hip_bfloat16* __restrict__ BT,
             const float* __restrict__ biasA, const float* __restrict__ biasB, int bsplit,
             void* __restrict__ Cout, int M, int N, int K) {
  __shared__ __align__(16) __hip_bfloat16 As[128 * 32];
  __shared__ __align__(16) __hip_bfloat16 Bs[128 * 32];
  const int tid = threadIdx.x;
  const int lane = tid & 63;
  const int wid = tid >> 6;
  const int wr = wid >> 1, wc = wid & 1;
  const int fr = lane & 15, fq = lane >> 4;
  const int m0 = blockIdx.y * 128;
  const int n0 = blockIdx.x * 128;

  // staging: chunk c = tid (and tid+256): row c/4, k-part (c%4)*8, LDS byte c*16
  const __hip_bfloat16* Ag = A + (size_t)(m0 + (tid >> 2)) * K + (tid & 3) * 8;
  const __hip_bfloat16* Ag2 = Ag + (size_t)64 * K;
  const __hip_bfloat16* Bg = BT + (size_t)(n0 + (tid >> 2)) * K + (tid & 3) * 8;
  const __hip_bfloat16* Bg2 = Bg + (size_t)64 * K;
  char* AsB = (char*)&As[0] + wid * 1024;
  char* BsB = (char*)&Bs[0] + wid * 1024;

  f32x4 acc[4][4] = {};

  const int ksteps = K >> 5;
  for (int ks = 0; ks < ksteps; ++ks) {
    __syncthreads();  // prior reads done before overwrite
    gload16(Ag, AsB);
    gload16(Ag2, AsB + 4096);
    gload16(Bg, BsB);
    gload16(Bg2, BsB + 4096);
    Ag += 32; Ag2 += 32; Bg += 32; Bg2 += 32;
    __syncthreads();  // drains vmcnt -> staged data visible

    bf16x8 af[4], bfr[4];
#pragma unroll
    for (int i = 0; i < 4; ++i)
      af[i] = *(const bf16x8*)&As[(wr * 64 + i * 16 + fr) * 32 + fq * 8];
#pragma unroll
    for (int j = 0; j < 4; ++j)
      bfr[j] = *(const bf16x8*)&Bs[(wc * 64 + j * 16 + fr) * 32 + fq * 8];
#pragma unroll
    for (int i = 0; i < 4; ++i)
#pragma unroll
      for (int j = 0; j < 4; ++j)
        acc[i][j] = __builtin_amdgcn_mfma_f32_16x16x32_bf16(af[i], bfr[j], acc[i][j], 0, 0, 0);
  }

  // epilogue: C/D layout col=lane&15, row=(lane>>4)*4+reg
#pragma unroll
  for (int j = 0; j < 4; ++j) {
    int col = n0 + wc * 64 + j * 16 + fr;
    float bv = (col < bsplit) ? biasA[col] : biasB[col - bsplit];
#pragma unroll
    for (int i = 0; i < 4; ++i) {
#pragma unroll
      for (int r = 0; r < 4; ++r) {
        int row = m0 + wr * 64 + i * 16 + fq * 4 + r;
        float v = fmaxf(acc[i][j][r] + bv, 0.f);
        if (OUT_BF16)
          ((__hip_bfloat16*)Cout)[(size_t)row * N + col] = __float2bfloat16(v);
        else
          ((float*)Cout)[(size_t)row * N + col] = v;
      }
    }
  }
}

// ---------------- launch ----------------

extern "C" void kernel_launch(void* const* d_in, const int* in_sizes, int n_in,
                              void* d_out, int out_size, void* d_ws, size_t ws_size,
                              hipStream_t stream) {
  const float* motion = (const float*)d_in[0];
  const float* robot  = (const float*)d_in[1];
  const float* z      = (const float*)d_in[2];
  const float* W_ms   = (const float*)d_in[3];
  const float* b_ms   = (const float*)d_in[4];
  const float* W_rs   = (const float*)d_in[5];
  const float* b_rs   = (const float*)d_in[6];
  const float* W_cmb  = (const float*)d_in[7];
  const float* b_cmb  = (const float*)d_in[8];
  const float* W_om   = (const float*)d_in[9];
  const float* b_om   = (const float*)d_in[10];
  const float* W_mu   = (const float*)d_in[11];
  const float* b_mu   = (const float*)d_in[12];
  const float* W_b    = (const float*)d_in[13];
  const float* b_b    = (const float*)d_in[14];
  const float* Wr0    = (const float*)d_in[15];
  const float* Wi0    = (const float*)d_in[16];
  const float* br0    = (const float*)d_in[17];
  const float* bi0    = (const float*)d_in[18];
  const float* Wr1    = (const float*)d_in[19];
  const float* Wi1    = (const float*)d_in[20];
  const float* br1    = (const float*)d_in[21];
  const float* bi1    = (const float*)d_in[22];
  const float* Wr2    = (const float*)d_in[23];
  const float* Wi2    = (const float*)d_in[24];
  const float* br2    = (const float*)d_in[25];
  // bi2 (d_in[26]) unused: yi of last layer is sliced away by [:, :, :256]

  float* out  = (float*)d_out;            // [25600,256], m = b*100+t
  float* zout = out + (size_t)6553600;    // [256,1024]
  float* omg  = zout + 262144;            // [256]
  float* muo  = omg + 256;                // [256,512]
  float* bbo  = muo + 131072;             // [256,512]

  char* ws = (char*)d_ws;
  float* stcat = (float*)ws;                               // 256*512 f32
  float* st    = stcat + 256 * 512;                        // 256*512 f32
  __hip_bfloat16* BT0 = (__hip_bfloat16*)(st + 256 * 512); // [2048,1024]
  __hip_bfloat16* BT1 = BT0 + (size_t)2048 * 1024;         // [1024,2048]
  __hip_bfloat16* BT2 = BT1 + (size_t)1024 * 2048;         // [256,1024]
  __hip_bfloat16* A0  = BT2 + (size_t)256 * 1024;          // [25600,1024]
  __hip_bfloat16* C1  = A0 + (size_t)25600 * 1024;         // [25600,2048]
  __hip_bfloat16* C2  = C1 + (size_t)25600 * 2048;         // [25600,1024]

  enc1<<<256, 512, 0, stream>>>(motion, robot, W_ms, b_ms, W_rs, b_rs, stcat);
  enc2<<<256, 512, 0, stream>>>(stcat, W_cmb, b_cmb, st);
  enc3<<<256, 512, 0, stream>>>(st, W_mu, b_mu, W_b, b_b, W_om, b_om, muo, bbo, omg);

  dim3 tb(32, 8);
  // BT0 = [[Wr0, Wi0], [-Wi0, Wr0]]^T   (Wr0/Wi0: [512,1024])
  tpack<<<dim3(32, 16), tb, 0, stream>>>(Wr0, 512, 1024,  1.f, BT0, 1024);
  tpack<<<dim3(32, 16), tb, 0, stream>>>(Wi0, 512, 1024,  1.f, BT0 + (size_t)1024 * 1024, 1024);
  tpack<<<dim3(32, 16), tb, 0, stream>>>(Wi0, 512, 1024, -1.f, BT0 + 512, 1024);
  tpack<<<dim3(32, 16), tb, 0, stream>>>(Wr0, 512, 1024,  1.f, BT0 + (size_t)1024 * 1024 + 512, 1024);
  // BT1 (Wr1/Wi1: [1024,512])
  tpack<<<dim3(16, 32), tb, 0, stream>>>(Wr1, 1024, 512,  1.f, BT1, 2048);
  tpack<<<dim3(16, 32), tb, 0, stream>>>(Wi1, 1024, 512,  1.f, BT1 + (size_t)512 * 2048, 2048);
  tpack<<<dim3(16, 32), tb, 0, stream>>>(Wi1, 1024, 512, -1.f, BT1 + 1024, 2048);
  tpack<<<dim3(16, 32), tb, 0, stream>>>(Wr1, 1024, 512,  1.f, BT1 + (size_t)512 * 2048 + 1024, 2048);
  // BT2 = [Wr2; -Wi2]^T  (Wr2/Wi2: [512,256])
  tpack<<<dim3(8, 16), tb, 0, stream>>>(Wr2, 512, 256,  1.f, BT2, 1024);
  tpack<<<dim3(8, 16), tb, 0, stream>>>(Wi2, 512, 256, -1.f, BT2 + 512, 1024);

  hopf_traj<<<256, 512, 0, stream>>>(z, omg, muo, bbo, A0, zout);

  gemm_bt<1><<<dim3(16, 200), 256, 0, stream>>>(A0, BT0, br0, bi0, 1024, C1, 25600, 2048, 1024);
  gemm_bt<1><<<dim3(8, 200), 256, 0, stream>>>(C1, BT1, br1, bi1, 512, C2, 25600, 1024, 2048);
  gemm_bt<0><<<dim3(2, 200), 256, 0, stream>>>(C2, BT2, br2, br2, 256, out, 25600, 256, 1024);
}

// Round 4
// 358.586 us; speedup vs baseline: 1.2294x; 1.1978x over previous
//
#include <hip/hip_runtime.h>
#include <hip/hip_bf16.h>

#define UNITS 512
#define STEPS 100
#define BATCH 256
#define DTC 0.001f

typedef __attribute__((ext_vector_type(8))) short bf16x8;
typedef __attribute__((ext_vector_type(4))) float f32x4;

__device__ __forceinline__ void gload16(const void* g, void* l) {
  __builtin_amdgcn_global_load_lds(
      (const __attribute__((address_space(1))) void*)g,
      (__attribute__((address_space(3))) void*)l,
      16, 0, 0);
}

// ---------------- encoder (fp32, accuracy-critical) ----------------

__global__ void enc1(const float* __restrict__ ms_in, const float* __restrict__ rs_in,
                     const float* __restrict__ Wms, const float* __restrict__ bms,
                     const float* __restrict__ Wrs, const float* __restrict__ brs,
                     float* __restrict__ stcat) {
  int b = blockIdx.x;
  int n = threadIdx.x;  // 512
  __shared__ float s[192];
  if (n < 64) s[n] = ms_in[b * 64 + n];
  else if (n < 192) s[n] = rs_in[b * 128 + (n - 64)];
  __syncthreads();
  float acc;
  if (n < 256) {
    acc = bms[n];
    for (int k = 0; k < 64; ++k) acc += s[k] * Wms[k * 256 + n];
  } else {
    int nn = n - 256;
    acc = brs[nn];
    for (int k = 0; k < 128; ++k) acc += s[64 + k] * Wrs[k * 256 + nn];
  }
  stcat[b * 512 + n] = fmaxf(acc, 0.f);
}

__global__ void enc2(const float* __restrict__ stcat, const float* __restrict__ Wc,
                     const float* __restrict__ bc, float* __restrict__ st) {
  int b = blockIdx.x;
  int n = threadIdx.x;  // 512
  __shared__ float s[512];
  s[n] = stcat[b * 512 + n];
  __syncthreads();
  float acc = bc[n];
  for (int k = 0; k < 512; ++k) acc += s[k] * Wc[k * 512 + n];
  st[b * 512 + n] = fmaxf(acc, 0.f);
}

__global__ void enc3(const float* __restrict__ st,
                     const float* __restrict__ Wmu, const float* __restrict__ bmu,
                     const float* __restrict__ Wb, const float* __restrict__ bbias,
                     const float* __restrict__ Wom, const float* __restrict__ bom,
                     float* __restrict__ mu_out, float* __restrict__ bb_out,
                     float* __restrict__ om_out) {
  int b = blockIdx.x;
  int n = threadIdx.x;  // 512
  __shared__ float s[512];
  __shared__ float red[512];
  s[n] = st[b * 512 + n];
  __syncthreads();
  float am = bmu[n], ab = bbias[n];
  for (int k = 0; k < 512; ++k) {
    float sv = s[k];
    am += sv * Wmu[k * 512 + n];
    ab += sv * Wb[k * 512 + n];
  }
  mu_out[b * 512 + n] = fabsf(fmaxf(am, 0.f));
  bb_out[b * 512 + n] = fabsf(fmaxf(ab, 0.f));
  red[n] = s[n] * Wom[n];  // W_om is [512,1]
  __syncthreads();
  for (int off = 256; off > 0; off >>= 1) {
    if (n < off) red[n] += red[n + off];
    __syncthreads();
  }
  if (n == 0) om_out[b] = fabsf(fmaxf(red[0] + bom[0], 0.f));
}

// ---------------- weight transpose+pack (fp32 -> bf16 B^T quadrants) ----------------

__global__ void tpack(const float* __restrict__ src, int R, int C, float sign,
                      __hip_bfloat16* __restrict__ dst, int ds) {
  // dst[c*ds + r] = bf16(sign * src[r*C + c])
  __shared__ float tile[32][33];
  int cb = blockIdx.x * 32, rb = blockIdx.y * 32;
  int tx = threadIdx.x, ty = threadIdx.y;  // (32,8)
#pragma unroll
  for (int i = 0; i < 32; i += 8)
    tile[ty + i][tx] = src[(size_t)(rb + ty + i) * C + (cb + tx)];
  __syncthreads();
#pragma unroll
  for (int i = 0; i < 32; i += 8)
    dst[(size_t)(cb + ty + i) * ds + (rb + tx)] = __float2bfloat16(sign * tile[tx][ty + i]);
}

// ---------------- Hopf trajectory (fp32 state; emits bf16 GEMM input) ----------------

__global__ void hopf_traj(const float* __restrict__ z, const float* __restrict__ omega,
                          const float* __restrict__ mu, const float* __restrict__ bb,
                          __hip_bfloat16* __restrict__ A0, float* __restrict__ z_out) {
  int b = blockIdx.x;
  int j = threadIdx.x;  // 512
  float x = z[b * 1024 + j];
  float y = z[b * 1024 + 512 + j];
  float om = omega[b];
  float muv = mu[b * 512 + j];
  float bbv = bb[b * 512 + j];
  float w = om * (float)(j + 1);
  for (int t = 0; t < STEPS; ++t) {
    float r2 = x * x + y * y;
    float g = muv - r2;
    float nx = x + DTC * (g * x - w * y + bbv);
    float ny = y + DTC * (g * y + w * x);
    x = nx; y = ny;
    if (t == 0) {
      z_out[b * 1024 + j] = x;
      z_out[b * 1024 + 512 + j] = y;
    }
    size_t row = (size_t)b * STEPS + t;  // M-order: m = b*100 + t
    A0[row * 1024 + j] = __float2bfloat16(x);
    A0[row * 1024 + 512 + j] = __float2bfloat16(y);
  }
}

// ---------------- 128^2 bf16 MFMA GEMM (kept for GEMM3) ----------------

template <int OUT_BF16>
__global__ __launch_bounds__(256)
void gemm_bt(const __hip_bfloat16* __restrict__ A, const __hip_bfloat16* __restrict__ BT,
             const float* __restrict__ biasA, const float* __restrict__ biasB, int bsplit,
             void* __restrict__ Cout, int M, int N, int K) {
  __shared__ __align__(16) __hip_bfloat16 As[128 * 32];
  __shared__ __align__(16) __hip_bfloat16 Bs[128 * 32];
  const int tid = threadIdx.x;
  const int lane = tid & 63;
  const int wid = tid >> 6;
  const int wr = wid >> 1, wc = wid & 1;
  const int fr = lane & 15, fq = lane >> 4;
  const int m0 = blockIdx.y * 128;
  const int n0 = blockIdx.x * 128;

  const __hip_bfloat16* Ag = A + (size_t)(m0 + (tid >> 2)) * K + (tid & 3) * 8;
  const __hip_bfloat16* Ag2 = Ag + (size_t)64 * K;
  const __hip_bfloat16* Bg = BT + (size_t)(n0 + (tid >> 2)) * K + (tid & 3) * 8;
  const __hip_bfloat16* Bg2 = Bg + (size_t)64 * K;
  char* AsB = (char*)&As[0] + wid * 1024;
  char* BsB = (char*)&Bs[0] + wid * 1024;

  f32x4 acc[4][4] = {};

  const int ksteps = K >> 5;
  for (int ks = 0; ks < ksteps; ++ks) {
    __syncthreads();
    gload16(Ag, AsB);
    gload16(Ag2, AsB + 4096);
    gload16(Bg, BsB);
    gload16(Bg2, BsB + 4096);
    Ag += 32; Ag2 += 32; Bg += 32; Bg2 += 32;
    __syncthreads();

    bf16x8 af[4], bfr[4];
#pragma unroll
    for (int i = 0; i < 4; ++i)
      af[i] = *(const bf16x8*)&As[(wr * 64 + i * 16 + fr) * 32 + fq * 8];
#pragma unroll
    for (int j = 0; j < 4; ++j)
      bfr[j] = *(const bf16x8*)&Bs[(wc * 64 + j * 16 + fr) * 32 + fq * 8];
#pragma unroll
    for (int i = 0; i < 4; ++i)
#pragma unroll
      for (int j = 0; j < 4; ++j)
        acc[i][j] = __builtin_amdgcn_mfma_f32_16x16x32_bf16(af[i], bfr[j], acc[i][j], 0, 0, 0);
  }

#pragma unroll
  for (int j = 0; j < 4; ++j) {
    int col = n0 + wc * 64 + j * 16 + fr;
    float bv = (col < bsplit) ? biasA[col] : biasB[col - bsplit];
#pragma unroll
    for (int i = 0; i < 4; ++i) {
#pragma unroll
      for (int r = 0; r < 4; ++r) {
        int row = m0 + wr * 64 + i * 16 + fq * 4 + r;
        float v = fmaxf(acc[i][j][r] + bv, 0.f);
        if (OUT_BF16)
          ((__hip_bfloat16*)Cout)[(size_t)row * N + col] = __float2bfloat16(v);
        else
          ((float*)Cout)[(size_t)row * N + col] = v;
      }
    }
  }
}

// ---------------- 256^2 8-wave 4-phase bf16 MFMA GEMM (T1+T2+T3+T4+T5) ----------------
// A [M,K] row-major bf16; BT [N,K] row-major bf16. C = relu(A@BT^T + bias), bf16 out.
// BM=BN=256, BK=64, 512 threads = 8 waves (2Mx4N), per-wave out 128x64.
// LDS 128 KiB dynamic: [2 buf][A 32K | B 32K]; tile stored as swizzled 16B chunks:
//   slot(row, c8) = row*8 + (c8 ^ (row&7))   (c8 = k/8 within BK=64)
// gload_lds dest linear; source pre-swizzled (rule #21). Raw s_barrier + counted
// vmcnt(2) once per K-tile keeps next-tile prefetch in flight across barriers.

#define LOAD_A(a, cb) do { _Pragma("unroll") for (int i = 0; i < 4; ++i) { \
  af[i][0] = *(const bf16x8*)((cb) + aoff0 + ((a)*4+i)*2048); \
  af[i][1] = *(const bf16x8*)((cb) + aoff1 + ((a)*4+i)*2048); } } while(0)

#define LOAD_B(b, BF, cb) do { _Pragma("unroll") for (int j = 0; j < 2; ++j) { \
  BF[j][0] = *(const bf16x8*)((cb) + boff0 + ((b)*2+j)*2048); \
  BF[j][1] = *(const bf16x8*)((cb) + boff1 + ((b)*2+j)*2048); } } while(0)

#define MFMA_Q(a, b, BF) do { _Pragma("unroll") for (int i = 0; i < 4; ++i) \
  _Pragma("unroll") for (int j = 0; j < 2; ++j) { \
    acc[(a)*4+i][(b)*2+j] = __builtin_amdgcn_mfma_f32_16x16x32_bf16(af[i][0], BF[j][0], acc[(a)*4+i][(b)*2+j], 0, 0, 0); \
    acc[(a)*4+i][(b)*2+j] = __builtin_amdgcn_mfma_f32_16x16x32_bf16(af[i][1], BF[j][1], acc[(a)*4+i][(b)*2+j], 0, 0, 0); } } while(0)

__global__ __launch_bounds__(512, 2)
void gemm256(const __hip_bfloat16* __restrict__ A, const __hip_bfloat16* __restrict__ BT,
             const float* __restrict__ biasA, const float* __restrict__ biasB, int bsplit,
             __hip_bfloat16* __restrict__ Cout, int N, int K, int ntn) {
  extern __shared__ char lds[];  // 131072 bytes

  const int tid = threadIdx.x;
  const int lane = tid & 63;
  const int wid = tid >> 6;       // 0..7
  const int wr = wid >> 2;        // 0..1  (M half)
  const int wc = wid & 3;         // 0..3  (N quarter)
  const int fr = lane & 15, fq = lane >> 4;

  // XCD-aware bijective swizzle (grid % 8 == 0 guaranteed by launch)
  const int nwg = gridDim.x;
  int f = blockIdx.x;
  f = (f & 7) * (nwg >> 3) + (f >> 3);
  const int m0 = (f / ntn) * 256;
  const int n0 = (f % ntn) * 256;

  // staging source (pre-swizzled chunk): thread t covers row (t>>3), chunk c8v
  const int c8v = (tid & 7) ^ ((tid >> 3) & 7);
  const __hip_bfloat16* Asrc0 = A + (size_t)(m0 + (tid >> 3)) * K + c8v * 8;
  const __hip_bfloat16* Asrc1 = Asrc0 + (size_t)128 * K;
  const __hip_bfloat16* Bsrc0 = BT + (size_t)(n0 + (tid >> 3)) * K + c8v * 8;
  const __hip_bfloat16* Bsrc1 = Bsrc0 + (size_t)128 * K;

  // swizzled LDS read offsets (byte): slot = rowInHalf*8 + ((ks*4+fq) ^ (fr&7))
  const int x0 = fq ^ (fr & 7);
  const int aoff0 = wr * 16384 + fr * 128 + x0 * 16;
  const int aoff1 = wr * 16384 + fr * 128 + (x0 ^ 4) * 16;
  const int boff0 = 32768 + (wc >> 1) * 16384 + ((wc & 1) * 64 + fr) * 128 + x0 * 16;
  const int boff1 = 32768 + (wc >> 1) * 16384 + ((wc & 1) * 64 + fr) * 128 + (x0 ^ 4) * 16;

  auto stage = [&](const __hip_bfloat16* srcBase, int koff, char* dst) {
    gload16(srcBase + koff, dst + wid * 1024);
    gload16(srcBase + koff + (size_t)64 * K, dst + 8192 + wid * 1024);
  };

  // prologue: tile 0 -> buf 0 (8 loads in flight)
  stage(Asrc0, 0, lds);
  stage(Asrc1, 0, lds + 16384);
  stage(Bsrc0, 0, lds + 32768);
  stage(Bsrc1, 0, lds + 49152);

  f32x4 acc[8][4] = {};
  bf16x8 af[4][2], bfA[2][2], bfB[2][2];

  const int nk = K >> 6;
  for (int kt = 0; kt < nk - 1; ++kt) {
    const int cur = kt & 1;
    char* cb = lds + cur * 65536;
    char* nb = lds + (cur ^ 1) * 65536;
    const int ko = (kt + 1) << 6;
    // -------- phase 0: stage A-half0(next); wait cur landed; compute Q(0,0)
    __builtin_amdgcn_s_barrier();            // all waves done reading buffer 'nb'
    __builtin_amdgcn_sched_barrier(0);
    stage(Asrc0, ko, nb);
    __builtin_amdgcn_sched_barrier(0);
    asm volatile("s_waitcnt vmcnt(2)" ::: "memory");  // cur's 8 loads landed; 2 new in flight
    __builtin_amdgcn_s_barrier();            // cur visible to all waves
    __builtin_amdgcn_sched_barrier(0);
    LOAD_A(0, cb);
    LOAD_B(0, bfA, cb);
    __builtin_amdgcn_s_setprio(1); MFMA_Q(0, 0, bfA); __builtin_amdgcn_s_setprio(0);
    // -------- phase 1: stage A-half1; compute Q(0,1)
    __builtin_amdgcn_s_barrier();
    __builtin_amdgcn_sched_barrier(0);
    stage(Asrc1, ko, nb + 16384);
    LOAD_B(1, bfB, cb);
    __builtin_amdgcn_s_setprio(1); MFMA_Q(0, 1, bfB); __builtin_amdgcn_s_setprio(0);
    // -------- phase 2: stage B-half0; compute Q(1,1)
    __builtin_amdgcn_s_barrier();
    __builtin_amdgcn_sched_barrier(0);
    stage(Bsrc0, ko, nb + 32768);
    LOAD_A(1, cb);
    __builtin_amdgcn_s_setprio(1); MFMA_Q(1, 1, bfB); __builtin_amdgcn_s_setprio(0);
    // -------- phase 3: stage B-half1; compute Q(1,0)
    __builtin_amdgcn_s_barrier();
    __builtin_amdgcn_sched_barrier(0);
    stage(Bsrc1, ko, nb + 49152);
    __builtin_amdgcn_s_setprio(1); MFMA_Q(1, 0, bfA); __builtin_amdgcn_s_setprio(0);
  }
  // -------- final tile: compute-only
  {
    char* cb = lds + ((nk - 1) & 1) * 65536;
    __builtin_amdgcn_s_barrier();
    asm volatile("s_waitcnt vmcnt(0)" ::: "memory");
    __builtin_amdgcn_s_barrier();
    __builtin_amdgcn_sched_barrier(0);
    LOAD_A(0, cb);
    LOAD_B(0, bfA, cb);
    __builtin_amdgcn_s_setprio(1); MFMA_Q(0, 0, bfA); __builtin_amdgcn_s_setprio(0);
    LOAD_B(1, bfB, cb);
    __builtin_amdgcn_s_setprio(1); MFMA_Q(0, 1, bfB); __builtin_amdgcn_s_setprio(0);
    LOAD_A(1, cb);
    __builtin_amdgcn_s_setprio(1); MFMA_Q(1, 1, bfB); MFMA_Q(1, 0, bfA); __builtin_amdgcn_s_setprio(0);
  }

  // epilogue: bias + relu, bf16 store. C/D layout: col=lane&15, row=(lane>>4)*4+reg
#pragma unroll
  for (int nj = 0; nj < 4; ++nj) {
    const int col = n0 + wc * 64 + nj * 16 + fr;
    const float bv = (col < bsplit) ? biasA[col] : biasB[col - bsplit];
#pragma unroll
    for (int mi = 0; mi < 8; ++mi) {
#pragma unroll
      for (int r = 0; r < 4; ++r) {
        const int row = m0 + wr * 128 + mi * 16 + fq * 4 + r;
        float v = fmaxf(acc[mi][nj][r] + bv, 0.f);
        Cout[(size_t)row * N + col] = __float2bfloat16(v);
      }
    }
  }
}

// ---------------- launch ----------------

extern "C" void kernel_launch(void* const* d_in, const int* in_sizes, int n_in,
                              void* d_out, int out_size, void* d_ws, size_t ws_size,
                              hipStream_t stream) {
  const float* motion = (const float*)d_in[0];
  const float* robot  = (const float*)d_in[1];
  const float* z      = (const float*)d_in[2];
  const float* W_ms   = (const float*)d_in[3];
  const float* b_ms   = (const float*)d_in[4];
  const float* W_rs   = (const float*)d_in[5];
  const float* b_rs   = (const float*)d_in[6];
  const float* W_cmb  = (const float*)d_in[7];
  const float* b_cmb  = (const float*)d_in[8];
  const float* W_om   = (const float*)d_in[9];
  const float* b_om   = (const float*)d_in[10];
  const float* W_mu   = (const float*)d_in[11];
  const float* b_mu   = (const float*)d_in[12];
  const float* W_b    = (const float*)d_in[13];
  const float* b_b    = (const float*)d_in[14];
  const float* Wr0    = (const float*)d_in[15];
  const float* Wi0    = (const float*)d_in[16];
  const float* br0    = (const float*)d_in[17];
  const float* bi0    = (const float*)d_in[18];
  const float* Wr1    = (const float*)d_in[19];
  const float* Wi1    = (const float*)d_in[20];
  const float* br1    = (const float*)d_in[21];
  const float* bi1    = (const float*)d_in[22];
  const float* Wr2    = (const float*)d_in[23];
  const float* Wi2    = (const float*)d_in[24];
  const float* br2    = (const float*)d_in[25];
  // bi2 (d_in[26]) unused: yi of last layer is sliced away by [:, :, :256]

  float* out  = (float*)d_out;            // [25600,256], m = b*100+t
  float* zout = out + (size_t)6553600;    // [256,1024]
  float* omg  = zout + 262144;            // [256]
  float* muo  = omg + 256;                // [256,512]
  float* bbo  = muo + 131072;             // [256,512]

  char* ws = (char*)d_ws;
  float* stcat = (float*)ws;                               // 256*512 f32
  float* st    = stcat + 256 * 512;                        // 256*512 f32
  __hip_bfloat16* BT0 = (__hip_bfloat16*)(st + 256 * 512); // [2048,1024]
  __hip_bfloat16* BT1 = BT0 + (size_t)2048 * 1024;         // [1024,2048]
  __hip_bfloat16* BT2 = BT1 + (size_t)1024 * 2048;         // [256,1024]
  __hip_bfloat16* A0  = BT2 + (size_t)256 * 1024;          // [25600,1024]
  __hip_bfloat16* C1  = A0 + (size_t)25600 * 1024;         // [25600,2048]
  __hip_bfloat16* C2  = C1 + (size_t)25600 * 2048;         // [25600,1024]

  enc1<<<256, 512, 0, stream>>>(motion, robot, W_ms, b_ms, W_rs, b_rs, stcat);
  enc2<<<256, 512, 0, stream>>>(stcat, W_cmb, b_cmb, st);
  enc3<<<256, 512, 0, stream>>>(st, W_mu, b_mu, W_b, b_b, W_om, b_om, muo, bbo, omg);

  dim3 tb(32, 8);
  // BT0 = [[Wr0, Wi0], [-Wi0, Wr0]]^T   (Wr0/Wi0: [512,1024])
  tpack<<<dim3(32, 16), tb, 0, stream>>>(Wr0, 512, 1024,  1.f, BT0, 1024);
  tpack<<<dim3(32, 16), tb, 0, stream>>>(Wi0, 512, 1024,  1.f, BT0 + (size_t)1024 * 1024, 1024);
  tpack<<<dim3(32, 16), tb, 0, stream>>>(Wi0, 512, 1024, -1.f, BT0 + 512, 1024);
  tpack<<<dim3(32, 16), tb, 0, stream>>>(Wr0, 512, 1024,  1.f, BT0 + (size_t)1024 * 1024 + 512, 1024);
  // BT1 (Wr1/Wi1: [1024,512])
  tpack<<<dim3(16, 32), tb, 0, stream>>>(Wr1, 1024, 512,  1.f, BT1, 2048);
  tpack<<<dim3(16, 32), tb, 0, stream>>>(Wi1, 1024, 512,  1.f, BT1 + (size_t)512 * 2048, 2048);
  tpack<<<dim3(16, 32), tb, 0, stream>>>(Wi1, 1024, 512, -1.f, BT1 + 1024, 2048);
  tpack<<<dim3(16, 32), tb, 0, stream>>>(Wr1, 1024, 512,  1.f, BT1 + (size_t)512 * 2048 + 1024, 2048);
  // BT2 = [Wr2; -Wi2]^T  (Wr2/Wi2: [512,256])
  tpack<<<dim3(8, 16), tb, 0, stream>>>(Wr2, 512, 256,  1.f, BT2, 1024);
  tpack<<<dim3(8, 16), tb, 0, stream>>>(Wi2, 512, 256, -1.f, BT2 + 512, 1024);

  hopf_traj<<<256, 512, 0, stream>>>(z, omg, muo, bbo, A0, zout);

  // GEMM1: [25600,1024] x [2048,1024]^T -> C1 bf16   (100x8 = 800 blocks, %8==0)
  gemm256<<<800, 512, 131072, stream>>>(A0, BT0, br0, bi0, 1024, C1, 2048, 1024, 8);
  // GEMM2: [25600,2048] x [1024,2048]^T -> C2 bf16   (100x4 = 400 blocks, %8==0)
  gemm256<<<400, 512, 131072, stream>>>(C1, BT1, br1, bi1, 512, C2, 1024, 2048, 4);
  // GEMM3: [25600,1024] x [256,1024]^T -> out f32 (small; proven 128^2 kernel)
  gemm_bt<0><<<dim3(2, 200), 256, 0, stream>>>(C2, BT2, br2, br2, 256, out, 25600, 256, 1024);
}